// Round 10
// baseline (202.386 us; speedup 1.0000x reference)
//
#include <hip/hip_runtime.h>
#include <cstdint>

#define FP8_MAX_F 448.0f

typedef float floatx4 __attribute__((ext_vector_type(4)));
typedef int   intx4   __attribute__((ext_vector_type(4)));
typedef int   intx8   __attribute__((ext_vector_type(8)));

static constexpr int Mdim = 2048;
static constexpr int Ndim = 4096;
static constexpr int Kdim = 4096;
static constexpr int BM = 64;
static constexpr int BN = 128;
static constexpr int BK = 128;   // fp8 bytes of K per staged tile
static constexpr int KT = Kdim / BK;  // 32 K-iterations

// Pass geometry: 2048 blocks x 256 thr, exact cover:
// x = 2,097,152 float4 = 4/thread; w = 4,194,304 float4 = 8/thread.
static constexpr int QGRID = 2048;
static constexpr size_t NTHR = (size_t)QGRID * 256;  // 524288

__device__ __forceinline__ void async_load16(const void* g, void* l) {
  __builtin_amdgcn_global_load_lds((__attribute__((address_space(1))) void*)g,
                                   (__attribute__((address_space(3))) void*)l,
                                   16, 0, 0);
}

__device__ __forceinline__ float amax4(float m, float4 v) {
  return fmaxf(m, fmaxf(fmaxf(fabsf(v.x), fabsf(v.y)),
                        fmaxf(fabsf(v.z), fabsf(v.w))));
}

__device__ __forceinline__ unsigned int quant4(float4 v, float scale) {
  float a = fminf(fmaxf(v.x * scale, -FP8_MAX_F), FP8_MAX_F);
  float b = fminf(fmaxf(v.y * scale, -FP8_MAX_F), FP8_MAX_F);
  float c = fminf(fmaxf(v.z * scale, -FP8_MAX_F), FP8_MAX_F);
  float d = fminf(fmaxf(v.w * scale, -FP8_MAX_F), FP8_MAX_F);
  unsigned int r = 0;
  r = __builtin_amdgcn_cvt_pk_fp8_f32(a, b, r, false);
  r = __builtin_amdgcn_cvt_pk_fp8_f32(c, d, r, true);
  return r;
}

// ---------------------------------------------------------------------------
// Pass 1: streaming abs-max of BOTH tensors, per-block partials (no atomics,
// no init) — round-9 version, verbatim. Non-gemm time is invariant to pass
// structure (5 variants, 135-141us) -> passes are at floor; don't touch.
// ---------------------------------------------------------------------------
__global__ __launch_bounds__(256)
void amax_partials(const float* __restrict__ x, const float* __restrict__ w,
                   float* __restrict__ partx, float* __restrict__ partw) {
  const int tid = threadIdx.x;
  const int bid = blockIdx.x;
  const size_t g = (size_t)bid * 256 + tid;
  const float4* x4 = (const float4*)x;
  const float4* w4 = (const float4*)w;

  float4 vx[4], vw[8];
#pragma unroll
  for (int t = 0; t < 4; t++) vx[t] = x4[g + (size_t)t * NTHR];
#pragma unroll
  for (int t = 0; t < 8; t++) vw[t] = w4[g + (size_t)t * NTHR];

  float mx = 0.f, mw = 0.f;
#pragma unroll
  for (int t = 0; t < 4; t++) mx = amax4(mx, vx[t]);
#pragma unroll
  for (int t = 0; t < 8; t++) mw = amax4(mw, vw[t]);
#pragma unroll
  for (int off = 32; off > 0; off >>= 1) {
    mx = fmaxf(mx, __shfl_down(mx, off, 64));
    mw = fmaxf(mw, __shfl_down(mw, off, 64));
  }
  __shared__ float rx[4], rw[4];
  if ((tid & 63) == 0) { rx[tid >> 6] = mx; rw[tid >> 6] = mw; }
  __syncthreads();
  if (tid == 0) {
    partx[bid] = fmaxf(fmaxf(rx[0], rx[1]), fmaxf(rx[2], rx[3]));
    partw[bid] = fmaxf(fmaxf(rw[0], rw[1]), fmaxf(rw[2], rw[3]));
  }
}

// ---------------------------------------------------------------------------
// Pass 2: per-block redundant reduce of partials (16 KB, L2/L3-hot), then
// quantize fp32 -> fp8 e4m3fn (RNE via v_cvt_pk_fp8_f32, same OCP grid as
// jnp float8_e4m3fn). Round-9 version, verbatim. Arithmetic mirrors the
// reference exactly: amax=max(|t|,1e-12); scale=448/amax; clip; round.
// ---------------------------------------------------------------------------
__global__ __launch_bounds__(256)
void quant_both(const float* __restrict__ x, const float* __restrict__ w,
                const float* __restrict__ partx, const float* __restrict__ partw,
                unsigned int* __restrict__ qx, unsigned int* __restrict__ qw,
                float* __restrict__ scalars) {
  const int tid = threadIdx.x;
  const int bid = blockIdx.x;
  const size_t g = (size_t)bid * 256 + tid;
  const float4* x4 = (const float4*)x;
  const float4* w4 = (const float4*)w;

  float ax = 0.f, aw = 0.f;
#pragma unroll
  for (int i = 0; i < QGRID / 256; i++) {
    ax = fmaxf(ax, partx[tid + i * 256]);
    aw = fmaxf(aw, partw[tid + i * 256]);
  }
#pragma unroll
  for (int off = 32; off > 0; off >>= 1) {
    ax = fmaxf(ax, __shfl_down(ax, off, 64));
    aw = fmaxf(aw, __shfl_down(aw, off, 64));
  }
  __shared__ float rx[4], rw[4];
  __shared__ float sxs, sws;
  if ((tid & 63) == 0) { rx[tid >> 6] = ax; rw[tid >> 6] = aw; }
  __syncthreads();
  if (tid == 0) {
    float fax = fmaxf(fmaxf(fmaxf(rx[0], rx[1]), fmaxf(rx[2], rx[3])), 1e-12f);
    float faw = fmaxf(fmaxf(fmaxf(rw[0], rw[1]), fmaxf(rw[2], rw[3])), 1e-12f);
    sxs = FP8_MAX_F / fax;
    sws = FP8_MAX_F / faw;
    if (bid == 0) { scalars[0] = fax; scalars[1] = faw; }
  }
  __syncthreads();
  const float sx = sxs, sw = sws;

#pragma unroll
  for (int t = 0; t < 4; t++)
    qx[g + (size_t)t * NTHR] = quant4(x4[g + (size_t)t * NTHR], sx);
#pragma unroll
  for (int t = 0; t < 8; t++)
    qw[g + (size_t)t * NTHR] = quant4(w4[g + (size_t)t * NTHR], sw);
}

// ---------------------------------------------------------------------------
// FP8 GEMM (mfma_scale_f32_16x16x128_f8f6f4, unit e8m0 scales). R13:
// 3-blocks/CU geometry on the 4x-validated R4 loop. Evidence: the ONLY
// positive mechanism on this problem is cross-block drain hiding (R4 2blk/CU
// 43.4 > R5 1blk/CU 44.8 despite R5's -33% LDS traffic); waves/CU also
// matters (R7 8w/CU 45.4 < R4 16w/CU 43.4). All explicit-schedule attempts
// (counted vmcnt, 4-phase, 8-phase) regressed -> loop structure untouched:
// per K-iter [__syncthreads drains last iter's loads] [issue 3 async16 for
// kt+1] [compute kt]. This round pushes the co-residency axis:
//   BM=64 x BN=128, BK=128, 512 thr = 8 waves (2Mx4N), wave = 32x32
//   (acc[2][2]), LDS = 2x(64+128)x128 = 48 KB -> 3 blocks/CU, 24 waves/CU
//   (3 independent barrier groups interleave their drains; vs R4's 2).
// Grid 32x32 = 1024 blocks. Budget: LDS pipe ~2060 cyc/K-step/CU, MFMA
// ~816 cyc/SIMD; 3-group interleave should pull K-step from 3260 toward
// the LDS bound -> predict 34-39us, MfmaUtil 36-42%.
//
// LDS rows of 128B = 8 chunks of 16B, XOR-swizzled: logical chunk c of row
// r at physical chunk c ^ (r&7). Staging pins LDS dst to tid*16 per 8KB
// round (64 rows; round steps keep row&7 invariant) and pre-swizzles the
// global source column. Fragment layouts (HW-verified m89/m148 + 5 passing
// rounds): A: lane holds A[m=lane&15][k=(lane>>4)*32+j], j=0..31;
// C/D: col=lane&15, row=(lane>>4)*4+reg_idx.
// ---------------------------------------------------------------------------
__launch_bounds__(512, 6)
__global__ void gemm_fp8(const unsigned char* __restrict__ qx,
                         const unsigned char* __restrict__ qw,
                         const float* __restrict__ bias,
                         const float* __restrict__ scalars,
                         float* __restrict__ out) {
  __shared__ __align__(16) unsigned char As[2 * BM * BK];  // 2 x 8 KiB
  __shared__ __align__(16) unsigned char Bs[2 * BN * BK];  // 2 x 16 KiB

  const int tid = threadIdx.x;   // 0..511
  const int lane = tid & 63;
  const int wv = tid >> 6;       // 0..7
  const int wm = (wv & 1) * 32;  // wave M offset (2 rows of waves)
  const int wn = (wv >> 1) * 32; // wave N offset (4 cols of waves)
  const int bm0 = blockIdx.y * BM;
  const int bn0 = blockIdx.x * BN;

  // Staging source map: 3 async16 per thread per K-tile (A: 1 round of 64
  // rows; B: 2 rounds of 64 rows), LDS dst pinned to tid*16 per 8KB round.
  const int srow = tid >> 3;                          // 0..63
  const int sc = ((tid & 7) ^ ((tid >> 3) & 7)) << 4; // swizzled source col
  const unsigned char* gA0 = qx + (size_t)(bm0 + srow) * Kdim + sc;
  const unsigned char* gB0 = qw + (size_t)(bn0 + srow) * Kdim + sc;
  const size_t rstep = (size_t)64 * Kdim;
  const int lslot = tid * 16;

  floatx4 acc[2][2];
#pragma unroll
  for (int i = 0; i < 2; i++)
#pragma unroll
    for (int j = 0; j < 2; j++) acc[i][j] = (floatx4){0.f, 0.f, 0.f, 0.f};

  // Fragment read constants
  const int frow = lane & 15;
  const int h = lane >> 4;                   // k-block 0..3 (32B each)
  const int fr7 = frow & 7;
  const int kc0 = ((2 * h) ^ fr7) << 4;      // phys offset of logical chunk 2h
  const int kc1 = ((2 * h + 1) ^ fr7) << 4;  // phys offset of chunk 2h+1

  // Prologue: stage tile 0 into buffer 0
  async_load16(gA0, As + lslot);
  async_load16(gB0, Bs + lslot);
  async_load16(gB0 + rstep, Bs + 8192 + lslot);

  for (int kt = 0; kt < KT; ++kt) {
    __syncthreads();  // drains loads issued LAST iter (a full compute ago);
                      // the 2 co-resident sibling blocks hide the drain.
    const int abuf = (kt & 1) * 8192;
    const int bbuf = (kt & 1) * 16384;
    if (kt + 1 < KT) {
      const int anb = ((kt + 1) & 1) * 8192;
      const int bnb = ((kt + 1) & 1) * 16384;
      const int k0 = (kt + 1) * BK;
      async_load16(gA0 + k0, As + anb + lslot);
      async_load16(gB0 + k0, Bs + bnb + lslot);
      async_load16(gB0 + k0 + rstep, Bs + bnb + 8192 + lslot);
    }

    intx8 af[2], bf[2];
#pragma unroll
    for (int t = 0; t < 2; t++) {
      const unsigned char* ra = As + abuf + (wm + t * 16 + frow) * BK;
      intx4 lo = *(const intx4*)(ra + kc0);
      intx4 hi = *(const intx4*)(ra + kc1);
      af[t] = __builtin_shufflevector(lo, hi, 0, 1, 2, 3, 4, 5, 6, 7);
    }
#pragma unroll
    for (int u = 0; u < 2; u++) {
      const unsigned char* rb = Bs + bbuf + (wn + u * 16 + frow) * BK;
      intx4 lo = *(const intx4*)(rb + kc0);
      intx4 hi = *(const intx4*)(rb + kc1);
      bf[u] = __builtin_shufflevector(lo, hi, 0, 1, 2, 3, 4, 5, 6, 7);
    }
#pragma unroll
    for (int i = 0; i < 2; i++)
#pragma unroll
      for (int j = 0; j < 2; j++)
        acc[i][j] = __builtin_amdgcn_mfma_scale_f32_16x16x128_f8f6f4(
            af[i], bf[j], acc[i][j], 0 /*A=fp8*/, 0 /*B=fp8*/,
            0, 0x7F7F7F7F, 0, 0x7F7F7F7F);  // unit scales (e8m0 127 = 2^0)
  }

  // Dequant scale, mirroring reference fp32 arithmetic exactly.
  float ax = fmaxf(scalars[0], 1e-12f);
  float aw = fmaxf(scalars[1], 1e-12f);
  float cs = (1.0f / (FP8_MAX_F / ax)) * (1.0f / (FP8_MAX_F / aw));

  const int crow = bm0 + wm + (lane >> 4) * 4;
  const int ccol = bn0 + wn + (lane & 15);
#pragma unroll
  for (int j = 0; j < 2; j++) {
    float bv = bias[ccol + j * 16];
#pragma unroll
    for (int i = 0; i < 2; i++) {
#pragma unroll
      for (int r = 0; r < 4; r++) {
        out[(size_t)(crow + i * 16 + r) * Ndim + (ccol + j * 16)] =
            acc[i][j][r] * cs + bv;
      }
    }
  }
}

extern "C" void kernel_launch(void* const* d_in, const int* in_sizes, int n_in,
                              void* d_out, int out_size, void* d_ws, size_t ws_size,
                              hipStream_t stream) {
  const float* x = (const float*)d_in[0];     // [M,K] fp32
  const float* w = (const float*)d_in[1];     // [N,K] fp32
  const float* bias = (const float*)d_in[2];  // [N] fp32
  float* out = (float*)d_out;                 // [M,N] fp32

  // Workspace: partx[2048] | partw[2048] | scalars[2] | pad to 32 KiB | qx | qw
  float* partx = (float*)d_ws;
  float* partw = partx + QGRID;
  float* scalars = partw + QGRID;
  unsigned char* qx = (unsigned char*)d_ws + 32768;
  unsigned char* qw = qx + (size_t)Mdim * Kdim;

  amax_partials<<<QGRID, 256, 0, stream>>>(x, w, partx, partw);
  quant_both<<<QGRID, 256, 0, stream>>>(x, w, partx, partw,
                                        (unsigned int*)qx, (unsigned int*)qw,
                                        scalars);
  dim3 grid(Ndim / BN, Mdim / BM);  // 32 x 32 = 1024 blocks, 512 threads
  gemm_fp8<<<grid, 512, 0, stream>>>(qx, qw, bias, scalars, out);
}